// Round 1
// baseline (665.859 us; speedup 1.0000x reference)
//
#include <hip/hip_runtime.h>
#include <math.h>

#define BB 4
#define LL 1024
#define EE 1024
#define HH 16
#define DD 64

// ---------------------------------------------------------------------------
// Kernel 1: grouped 3x3 conv over (l, d) per head, + bias.
// qc[b,h,l,d] = bias[h] + sum_{i,j} query[b, l+i-1, h*D + d+j-1] * w[h,i,j]
// block = 256 threads = 4 l-rows x 64 d for one (b,h). grid = B*H*(L/4)
// ---------------------------------------------------------------------------
__global__ __launch_bounds__(256) void conv_kernel(
    const float* __restrict__ query,
    const float* __restrict__ conv_w,
    const float* __restrict__ conv_b,
    float* __restrict__ qc) {
    int tid = threadIdx.x;
    int d = tid & 63;
    int lr = tid >> 6;
    int tile = blockIdx.x;                 // B*H*(L/4)
    int l0 = (tile & (LL / 4 - 1)) << 2;   // L/4 = 256
    int bh = tile >> 8;
    int h = bh & (HH - 1);
    int b = bh >> 4;
    int l = l0 + lr;

    const float* w = conv_w + h * 9;
    float acc = conv_b[h];
    const float* qin = query + ((size_t)b * LL) * EE + h * DD;
    #pragma unroll
    for (int i = 0; i < 3; ++i) {
        int li = l + i - 1;
        if (li < 0 || li >= LL) continue;
        #pragma unroll
        for (int j = 0; j < 3; ++j) {
            int dj = d + j - 1;
            if (dj < 0 || dj >= DD) continue;
            acc += w[i * 3 + j] * qin[(size_t)li * EE + dj];
        }
    }
    qc[((size_t)bh * LL + l) * DD + d] = acc;
}

// ---------------------------------------------------------------------------
// Kernel 2: keys softmax over the SEQ dim (per (b,h,d) column), with
// Bernoulli mask -> -inf (i.e. excluded; output 0 at masked positions).
// one block of 1024 threads per (b,h). d = tid&63, seg = tid>>6 covers 64 l's.
// ---------------------------------------------------------------------------
__global__ __launch_bounds__(1024) void ksoftmax_kernel(
    const float* __restrict__ keys,
    const int* __restrict__ bern,
    float* __restrict__ ks) {
    __shared__ float red[16][64];
    int tid = threadIdx.x;
    int d = tid & 63;
    int seg = tid >> 6;
    int bh = blockIdx.x;
    int h = bh & (HH - 1);
    int b = bh >> 4;
    const float* kin = keys + ((size_t)b * LL) * EE + h * DD + d;
    const int* bm = bern + (size_t)bh * LL;
    int lbase = seg * 64;

    // pass 1: column max over unmasked
    float m = -INFINITY;
    for (int i = 0; i < 64; ++i) {
        int l = lbase + i;
        if (bm[l]) m = fmaxf(m, kin[(size_t)l * EE]);
    }
    red[seg][d] = m;
    __syncthreads();
    if (seg == 0) {
        float mm = red[0][d];
        #pragma unroll
        for (int s = 1; s < 16; ++s) mm = fmaxf(mm, red[s][d]);
        red[0][d] = mm;
    }
    __syncthreads();
    m = red[0][d];
    __syncthreads();

    // pass 2: sum of exp over unmasked
    float sum = 0.f;
    for (int i = 0; i < 64; ++i) {
        int l = lbase + i;
        if (bm[l]) sum += expf(kin[(size_t)l * EE] - m);
    }
    red[seg][d] = sum;
    __syncthreads();
    if (seg == 0) {
        float ss = red[0][d];
        #pragma unroll
        for (int s = 1; s < 16; ++s) ss += red[s][d];
        red[0][d] = ss;
    }
    __syncthreads();
    float inv = 1.f / red[0][d];

    // pass 3: write normalized (masked -> 0)
    float* kout = ks + (size_t)bh * LL * DD + d;
    for (int i = 0; i < 64; ++i) {
        int l = lbase + i;
        kout[(size_t)l * DD] = bm[l] ? expf(kin[(size_t)l * EE] - m) * inv : 0.f;
    }
}

// ---------------------------------------------------------------------------
// Kernel 3: per-head value linear: vl[b,h,l,e] = sum_d values[b,l,h*D+d]*Wv[e,d]
// block = 256, one (b,h, 16-row l-tile). Wv staged in LDS (+1 pad).
// ---------------------------------------------------------------------------
__global__ __launch_bounds__(256) void vlin_kernel(
    const float* __restrict__ values,
    const float* __restrict__ Wv,
    float* __restrict__ vl) {
    __shared__ float WvS[64][65];
    __shared__ float vs[16][64];
    int tid = threadIdx.x;
    int tile = blockIdx.x;                 // B*H*(L/16) = 4096
    int lt = tile & (LL / 16 - 1);
    int bh = tile >> 6;
    int h = bh & (HH - 1);
    int b = bh >> 4;
    int l0 = lt * 16;

    for (int idx = tid; idx < 64 * 64; idx += 256)
        WvS[idx >> 6][idx & 63] = Wv[idx];
    const float* vin = values + ((size_t)b * LL + l0) * EE + h * DD;
    for (int idx = tid; idx < 16 * 64; idx += 256)
        vs[idx >> 6][idx & 63] = vin[(size_t)(idx >> 6) * EE + (idx & 63)];
    __syncthreads();

    int e = tid & 63;
    int rg = tid >> 6;
    float* vout = vl + ((size_t)bh * LL + l0) * DD;
    for (int r = rg; r < 16; r += 4) {
        float acc = 0.f;
        #pragma unroll
        for (int dd = 0; dd < 64; ++dd)
            acc += vs[r][dd] * WvS[e][dd];
        vout[(size_t)r * DD + e] = acc;
    }
}

// ---------------------------------------------------------------------------
// Kernel 4: flash attention per (b,h, 64-row q-tile).
// energy = qc @ ks^T; masked cols (pad&causal==1) -> -1e20; softmax(e/32);
// out = attn @ vl.  256 threads, per-thread 4x4 register block.
// ---------------------------------------------------------------------------
#define STR 68   // LDS row stride (floats): keeps float4 alignment (68*4=272=17*16)

__global__ __launch_bounds__(256) void attn_kernel(
    const float* __restrict__ qc,
    const float* __restrict__ ks,
    const float* __restrict__ vl,
    const int* __restrict__ pad,
    const int* __restrict__ cau,
    float* __restrict__ out) {
    __shared__ float Qs[64][STR];
    __shared__ float Ks[64][STR];
    __shared__ float Vs[64][STR];
    __shared__ float Ps[64][STR];   // stored transposed: Ps[c][r]
    __shared__ int smask[64];

    int tid = threadIdx.x;
    int qt = blockIdx.x & 15;
    int bh = blockIdx.x >> 4;
    int h = bh & (HH - 1);
    int b = bh >> 4;
    int q0 = qt * 64;
    int tr = tid >> 4;   // rows 4tr..4tr+3
    int tc = tid & 15;   // cols 4tc..4tc+3

    // stage Q (float4)
    const float* qbase = qc + ((size_t)bh * LL + q0) * DD;
    for (int idx = tid; idx < 64 * 16; idx += 256) {
        int r = idx >> 4;
        int d4 = (idx & 15) << 2;
        *(float4*)&Qs[r][d4] = *(const float4*)&qbase[(size_t)r * DD + d4];
    }

    float o[4][4] = {};
    float m[4], lsum[4];
    #pragma unroll
    for (int i = 0; i < 4; ++i) { m[i] = -INFINITY; lsum[i] = 0.f; }
    const float inv32 = 0.03125f;

    for (int kt = 0; kt < 16; ++kt) {
        int k0 = kt * 64;
        const float* kbase = ks + ((size_t)bh * LL + k0) * DD;
        const float* vbase = vl + ((size_t)bh * LL + k0) * DD;
        for (int idx = tid; idx < 64 * 16; idx += 256) {
            int r = idx >> 4;
            int d4 = (idx & 15) << 2;
            *(float4*)&Ks[r][d4] = *(const float4*)&kbase[(size_t)r * DD + d4];
            *(float4*)&Vs[r][d4] = *(const float4*)&vbase[(size_t)r * DD + d4];
        }
        if (tid < 64)
            smask[tid] = (pad[b * LL + k0 + tid] != 0) && (cau[b * LL + k0 + tid] != 0);
        __syncthreads();

        // S = Q K^T (4x4 per thread)
        float s[4][4];
        #pragma unroll
        for (int i = 0; i < 4; ++i)
            #pragma unroll
            for (int j = 0; j < 4; ++j) s[i][j] = 0.f;
        #pragma unroll 4
        for (int dd = 0; dd < 64; dd += 4) {
            float4 qv[4], kv[4];
            #pragma unroll
            for (int i = 0; i < 4; ++i) qv[i] = *(const float4*)&Qs[4 * tr + i][dd];
            #pragma unroll
            for (int j = 0; j < 4; ++j) kv[j] = *(const float4*)&Ks[4 * tc + j][dd];
            #pragma unroll
            for (int i = 0; i < 4; ++i)
                #pragma unroll
                for (int j = 0; j < 4; ++j)
                    s[i][j] += qv[i].x * kv[j].x + qv[i].y * kv[j].y
                             + qv[i].z * kv[j].z + qv[i].w * kv[j].w;
        }
        // apply pad&causal mask (reference: where(mask, -1e20, energy))
        #pragma unroll
        for (int j = 0; j < 4; ++j)
            if (smask[4 * tc + j]) {
                #pragma unroll
                for (int i = 0; i < 4; ++i) s[i][j] = -1e20f;
            }

        // online softmax (logits = s/32)
        float p[4][4];
        #pragma unroll
        for (int i = 0; i < 4; ++i) {
            float t = fmaxf(fmaxf(s[i][0], s[i][1]), fmaxf(s[i][2], s[i][3]));
            #pragma unroll
            for (int w = 1; w < 16; w <<= 1)
                t = fmaxf(t, __shfl_xor(t, w, 64));
            float mnew = fmaxf(m[i], t);
            float scale = expf((m[i] - mnew) * inv32);
            float rs = 0.f;
            #pragma unroll
            for (int j = 0; j < 4; ++j) {
                p[i][j] = expf((s[i][j] - mnew) * inv32);
                rs += p[i][j];
            }
            #pragma unroll
            for (int w = 1; w < 16; w <<= 1)
                rs += __shfl_xor(rs, w, 64);
            lsum[i] = lsum[i] * scale + rs;
            m[i] = mnew;
            #pragma unroll
            for (int j = 0; j < 4; ++j) o[i][j] *= scale;
        }

        // store P transposed: Ps[c][r], float4 over r
        #pragma unroll
        for (int j = 0; j < 4; ++j) {
            float4 pj = { p[0][j], p[1][j], p[2][j], p[3][j] };
            *(float4*)&Ps[4 * tc + j][4 * tr] = pj;
        }
        __syncthreads();

        // O += P^T-read @ V : o[i][j] over e = 4tc+j
        for (int c = 0; c < 64; ++c) {
            float4 pv = *(const float4*)&Ps[c][4 * tr];  // p for rows 4tr..4tr+3
            float4 vv = *(const float4*)&Vs[c][4 * tc];
            o[0][0] += pv.x * vv.x; o[0][1] += pv.x * vv.y; o[0][2] += pv.x * vv.z; o[0][3] += pv.x * vv.w;
            o[1][0] += pv.y * vv.x; o[1][1] += pv.y * vv.y; o[1][2] += pv.y * vv.z; o[1][3] += pv.y * vv.w;
            o[2][0] += pv.z * vv.x; o[2][1] += pv.z * vv.y; o[2][2] += pv.z * vv.z; o[2][3] += pv.z * vv.w;
            o[3][0] += pv.w * vv.x; o[3][1] += pv.w * vv.y; o[3][2] += pv.w * vv.z; o[3][3] += pv.w * vv.w;
        }
        __syncthreads();
    }

    // normalize and write out[b, q0+r, h*64+e]
    #pragma unroll
    for (int i = 0; i < 4; ++i) {
        float invl = 1.f / lsum[i];
        float4 ov = { o[i][0] * invl, o[i][1] * invl, o[i][2] * invl, o[i][3] * invl };
        *(float4*)&out[((size_t)b * LL + q0 + 4 * tr + i) * EE + h * DD + 4 * tc] = ov;
    }
}

extern "C" void kernel_launch(void* const* d_in, const int* in_sizes, int n_in,
                              void* d_out, int out_size, void* d_ws, size_t ws_size,
                              hipStream_t stream) {
    const float* query = (const float*)d_in[0];
    const float* keys  = (const float*)d_in[1];
    const float* values = (const float*)d_in[2];
    const int* pad  = (const int*)d_in[3];
    const int* cau  = (const int*)d_in[4];
    const int* bern = (const int*)d_in[5];
    const float* conv_w = (const float*)d_in[6];
    const float* conv_b = (const float*)d_in[7];
    const float* Wv = (const float*)d_in[8];
    float* outp = (float*)d_out;

    const size_t per = (size_t)BB * HH * LL * DD;  // 4,194,304 floats
    float* qc = (float*)d_ws;
    float* ksm = qc + per;
    float* vlin = ksm + per;

    conv_kernel<<<BB * HH * (LL / 4), 256, 0, stream>>>(query, conv_w, conv_b, qc);
    ksoftmax_kernel<<<BB * HH, 1024, 0, stream>>>(keys, bern, ksm);
    vlin_kernel<<<BB * HH * (LL / 16), 256, 0, stream>>>(values, Wv, vlin);
    attn_kernel<<<BB * HH * 16, 256, 0, stream>>>(qc, ksm, vlin, pad, cau, outp);
}

// Round 2
// 165.389 us; speedup vs baseline: 4.0260x; 4.0260x over previous
//
#include <hip/hip_runtime.h>
#include <hip/hip_bf16.h>
#include <math.h>

#define BB 4
#define LL 1024
#define EE 1024
#define HH 16
#define DD 64

typedef __attribute__((ext_vector_type(8))) short short8;
typedef __attribute__((ext_vector_type(4))) float f32x4;

static __device__ __forceinline__ unsigned short bfbits(float x) {
    __hip_bfloat16 h = __float2bfloat16(x);
    return *(unsigned short*)&h;
}

// ---------------------------------------------------------------------------
// Kernel 1: grouped 3x3 conv over (l, d) per head, + bias -> bf16 qcb[bh][l][d]
// ---------------------------------------------------------------------------
__global__ __launch_bounds__(256) void conv_kernel(
    const float* __restrict__ query,
    const float* __restrict__ conv_w,
    const float* __restrict__ conv_b,
    __hip_bfloat16* __restrict__ qcb) {
    int tid = threadIdx.x;
    int d = tid & 63;
    int lr = tid >> 6;
    int tile = blockIdx.x;                 // B*H*(L/4)
    int l0 = (tile & (LL / 4 - 1)) << 2;
    int bh = tile >> 8;
    int h = bh & (HH - 1);
    int b = bh >> 4;
    int l = l0 + lr;

    const float* w = conv_w + h * 9;
    float acc = conv_b[h];
    const float* qin = query + ((size_t)b * LL) * EE + h * DD;
    #pragma unroll
    for (int i = 0; i < 3; ++i) {
        int li = l + i - 1;
        if (li < 0 || li >= LL) continue;
        #pragma unroll
        for (int j = 0; j < 3; ++j) {
            int dj = d + j - 1;
            if (dj < 0 || dj >= DD) continue;
            acc += w[i * 3 + j] * qin[(size_t)li * EE + dj];
        }
    }
    qcb[((size_t)bh * LL + l) * DD + d] = __float2bfloat16(acc);
}

// ---------------------------------------------------------------------------
// Kernel 2: keys softmax over SEQ dim with Bernoulli -inf mask -> bf16 ksb
// ---------------------------------------------------------------------------
__global__ __launch_bounds__(1024) void ksoftmax_kernel(
    const float* __restrict__ keys,
    const int* __restrict__ bern,
    __hip_bfloat16* __restrict__ ksb) {
    __shared__ float red[16][64];
    int tid = threadIdx.x;
    int d = tid & 63;
    int seg = tid >> 6;
    int bh = blockIdx.x;
    int h = bh & (HH - 1);
    int b = bh >> 4;
    const float* kin = keys + ((size_t)b * LL) * EE + h * DD + d;
    const int* bm = bern + (size_t)bh * LL;
    int lbase = seg * 64;

    float m = -INFINITY;
    for (int i = 0; i < 64; ++i) {
        int l = lbase + i;
        if (bm[l]) m = fmaxf(m, kin[(size_t)l * EE]);
    }
    red[seg][d] = m;
    __syncthreads();
    if (seg == 0) {
        float mm = red[0][d];
        #pragma unroll
        for (int s = 1; s < 16; ++s) mm = fmaxf(mm, red[s][d]);
        red[0][d] = mm;
    }
    __syncthreads();
    m = red[0][d];
    __syncthreads();

    float sum = 0.f;
    for (int i = 0; i < 64; ++i) {
        int l = lbase + i;
        if (bm[l]) sum += __expf(kin[(size_t)l * EE] - m);
    }
    red[seg][d] = sum;
    __syncthreads();
    if (seg == 0) {
        float ss = red[0][d];
        #pragma unroll
        for (int s = 1; s < 16; ++s) ss += red[s][d];
        red[0][d] = ss;
    }
    __syncthreads();
    float inv = 1.f / red[0][d];

    __hip_bfloat16* kout = ksb + (size_t)bh * LL * DD + d;
    for (int i = 0; i < 64; ++i) {
        int l = lbase + i;
        float v = bm[l] ? __expf(kin[(size_t)l * EE] - m) * inv : 0.f;
        kout[(size_t)l * DD] = __float2bfloat16(v);
    }
}

// ---------------------------------------------------------------------------
// Kernel 3: per-head value linear -> TRANSPOSED bf16 vt[bh][d][l]
// block = 256 threads, one (b,h, 64-row l-tile).
// ---------------------------------------------------------------------------
__global__ __launch_bounds__(256) void vlin_kernel(
    const float* __restrict__ values,
    const float* __restrict__ Wv,
    __hip_bfloat16* __restrict__ vt) {
    __shared__ float WvS[64][65];
    __shared__ float vs[64][68];
    int tid = threadIdx.x;
    int tile = blockIdx.x;                 // B*H*(L/64) = 1024
    int lt = tile & 15;
    int bh = tile >> 4;
    int h = bh & (HH - 1);
    int b = bh >> 4;
    int l0 = lt * 64;

    for (int idx = tid; idx < 64 * 64; idx += 256)
        WvS[idx >> 6][idx & 63] = Wv[idx];
    const float* vin = values + ((size_t)b * LL + l0) * EE + h * DD;
    for (int idx = tid; idx < 1024; idx += 256) {
        int r = idx >> 4;
        int c4 = (idx & 15) << 2;
        *(float4*)&vs[r][c4] = *(const float4*)&vin[(size_t)r * EE + c4];
    }
    __syncthreads();

    int d = tid & 63;
    int r0 = (tid >> 6) * 16;
    float acc[16];
    #pragma unroll
    for (int r = 0; r < 16; ++r) acc[r] = 0.f;
    for (int k = 0; k < 64; ++k) {
        float wv = WvS[d][k];   // e=d row of Wv (torch Linear: out_e = sum_d v_d * W[e][d])
        #pragma unroll
        for (int r = 0; r < 16; ++r) acc[r] += vs[r0 + r][k] * wv;
    }
    union { unsigned short us[16]; uint4 v[2]; } pk;
    #pragma unroll
    for (int r = 0; r < 16; ++r) pk.us[r] = bfbits(acc[r]);
    __hip_bfloat16* vo = vt + ((size_t)bh * DD + d) * LL + l0 + r0;
    *(uint4*)&vo[0] = pk.v[0];
    *(uint4*)&vo[8] = pk.v[1];
}

// ---------------------------------------------------------------------------
// Kernel 4: MFMA flash attention. 4 waves x 16 q-rows; kv tiles of 64.
// LDS tiles XOR-swizzled (pre-swizzled global source for global_load_lds).
// ---------------------------------------------------------------------------
__global__ __launch_bounds__(256) void attn_mfma_kernel(
    const __hip_bfloat16* __restrict__ qcb,
    const __hip_bfloat16* __restrict__ ksb,
    const __hip_bfloat16* __restrict__ vtb,
    const int* __restrict__ pad,
    const int* __restrict__ cau,
    float* __restrict__ out) {
    __shared__ __align__(16) short Qs[64 * 64];
    __shared__ __align__(16) short Ks[64 * 64];
    __shared__ __align__(16) short Vts[64 * 64];
    __shared__ __align__(16) short Ps[4][16 * 72];   // per-wave P, 144B pitch
    __shared__ int smask[64];

    int tid = threadIdx.x;
    int lane = tid & 63;
    int w = tid >> 6;
    int g = lane >> 4;
    int q15 = lane & 15;
    int qt = blockIdx.x & 15;
    int bh = blockIdx.x >> 4;
    int b = bh >> 4;
    int h = bh & 15;
    int q0 = qt * 64;

    // ---- stage Q tile (swizzled source -> linear LDS; read applies same XOR)
    const __hip_bfloat16* qsrc = qcb + ((size_t)bh * LL + q0) * DD;
    #pragma unroll
    for (int it = 0; it < 2; ++it) {
        int slot = it * 256 + tid;
        int row = slot >> 3, ch = slot & 7;
        const __hip_bfloat16* gp = qsrc + row * DD + ((ch ^ (row & 7)) << 3);
        __builtin_amdgcn_global_load_lds(
            (const __attribute__((address_space(1))) void*)gp,
            (__attribute__((address_space(3))) void*)(Qs + it * 2048 + w * 512),
            16, 0, 0);
    }

    f32x4 Oacc[4];
    float mrun[4], lrun[4];
    #pragma unroll
    for (int u = 0; u < 4; ++u) Oacc[u] = (f32x4){0.f, 0.f, 0.f, 0.f};
    #pragma unroll
    for (int r = 0; r < 4; ++r) { mrun[r] = -INFINITY; lrun[r] = 0.f; }
    const float inv32 = 0.03125f;

    const int* pb = pad + b * LL;
    const int* cb = cau + b * LL;
    short8 Qf0, Qf1;

    for (int kt = 0; kt < 16; ++kt) {
        int k0 = kt * 64;
        const __hip_bfloat16* ksrc = ksb + ((size_t)bh * LL + k0) * DD;
        const __hip_bfloat16* vsrc = vtb + (size_t)bh * DD * LL + k0;
        #pragma unroll
        for (int it = 0; it < 2; ++it) {
            int slot = it * 256 + tid;
            int row = slot >> 3, ch = slot & 7;
            int sw = (ch ^ (row & 7)) << 3;
            __builtin_amdgcn_global_load_lds(
                (const __attribute__((address_space(1))) void*)(ksrc + row * DD + sw),
                (__attribute__((address_space(3))) void*)(Ks + it * 2048 + w * 512),
                16, 0, 0);
            __builtin_amdgcn_global_load_lds(
                (const __attribute__((address_space(1))) void*)(vsrc + (size_t)row * LL + sw),
                (__attribute__((address_space(3))) void*)(Vts + it * 2048 + w * 512),
                16, 0, 0);
        }
        if (tid < 64)
            smask[tid] = (pb[k0 + tid] != 0) & (cb[k0 + tid] != 0);
        __syncthreads();   // drains vmcnt (incl. Q on first iter)

        if (kt == 0) {
            int qrow = 16 * w + q15;
            Qf0 = *(const short8*)&Qs[qrow * 64 + (((g + 0) ^ (q15 & 7)) << 3)];
            Qf1 = *(const short8*)&Qs[qrow * 64 + (((g + 4) ^ (q15 & 7)) << 3)];
        }

        // S = Q K^T : 4 kv subtiles x (K=64 as 2 mfma)
        f32x4 Sacc[4];
        #pragma unroll
        for (int t = 0; t < 4; ++t) Sacc[t] = (f32x4){0.f, 0.f, 0.f, 0.f};
        #pragma unroll
        for (int t = 0; t < 4; ++t) {
            int krow = 16 * t + q15;
            short8 Kf0 = *(const short8*)&Ks[krow * 64 + (((g + 0) ^ (q15 & 7)) << 3)];
            short8 Kf1 = *(const short8*)&Ks[krow * 64 + (((g + 4) ^ (q15 & 7)) << 3)];
            Sacc[t] = __builtin_amdgcn_mfma_f32_16x16x32_bf16(Qf0, Kf0, Sacc[t], 0, 0, 0);
            Sacc[t] = __builtin_amdgcn_mfma_f32_16x16x32_bf16(Qf1, Kf1, Sacc[t], 0, 0, 0);
        }

        // mask columns where pad & causal (reference: where(mask, -1e20, energy))
        #pragma unroll
        for (int t = 0; t < 4; ++t)
            if (smask[16 * t + q15]) {
                Sacc[t][0] = -1e20f; Sacc[t][1] = -1e20f;
                Sacc[t][2] = -1e20f; Sacc[t][3] = -1e20f;
            }

        // online softmax per q-row (row = 4g + r, duplicated across 16 col-lanes)
        #pragma unroll
        for (int r = 0; r < 4; ++r) {
            float mx = fmaxf(fmaxf(Sacc[0][r], Sacc[1][r]), fmaxf(Sacc[2][r], Sacc[3][r]));
            #pragma unroll
            for (int msk = 1; msk < 16; msk <<= 1)
                mx = fmaxf(mx, __shfl_xor(mx, msk, 64));
            float mnew = fmaxf(mrun[r], mx);
            float sc = __expf((mrun[r] - mnew) * inv32);
            float pr0 = __expf((Sacc[0][r] - mnew) * inv32);
            float pr1 = __expf((Sacc[1][r] - mnew) * inv32);
            float pr2 = __expf((Sacc[2][r] - mnew) * inv32);
            float pr3 = __expf((Sacc[3][r] - mnew) * inv32);
            float rs = pr0 + pr1 + pr2 + pr3;
            #pragma unroll
            for (int msk = 1; msk < 16; msk <<= 1)
                rs += __shfl_xor(rs, msk, 64);
            lrun[r] = lrun[r] * sc + rs;
            mrun[r] = mnew;
            #pragma unroll
            for (int u = 0; u < 4; ++u) {
                Oacc[u][r] *= sc;
            }
            int prow = (4 * g + r) * 72;
            Ps[w][prow + 0  + q15] = (short)bfbits(pr0);
            Ps[w][prow + 16 + q15] = (short)bfbits(pr1);
            Ps[w][prow + 32 + q15] = (short)bfbits(pr2);
            Ps[w][prow + 48 + q15] = (short)bfbits(pr3);
        }
        __syncthreads();   // P visible to all lanes; K/Vt reads done below

        // O += P V : A=P[q][kv] contiguous, B=V[kv][d] from Vt[d][kv] contiguous
        short8 Pf0 = *(const short8*)&Ps[w][q15 * 72 + 8 * g];
        short8 Pf1 = *(const short8*)&Ps[w][q15 * 72 + 8 * g + 32];
        #pragma unroll
        for (int u = 0; u < 4; ++u) {
            int vrow = 16 * u + q15;
            short8 Vf0 = *(const short8*)&Vts[vrow * 64 + (((g + 0) ^ (q15 & 7)) << 3)];
            short8 Vf1 = *(const short8*)&Vts[vrow * 64 + (((g + 4) ^ (q15 & 7)) << 3)];
            Oacc[u] = __builtin_amdgcn_mfma_f32_16x16x32_bf16(Pf0, Vf0, Oacc[u], 0, 0, 0);
            Oacc[u] = __builtin_amdgcn_mfma_f32_16x16x32_bf16(Pf1, Vf1, Oacc[u], 0, 0, 0);
        }
        __syncthreads();   // all waves done with Ks/Vts before next stage
    }

    // normalize and write out[b, q0+16w+4g+r, h*64 + 16u + q15]
    float invl[4];
    #pragma unroll
    for (int r = 0; r < 4; ++r) invl[r] = 1.f / lrun[r];
    #pragma unroll
    for (int u = 0; u < 4; ++u) {
        #pragma unroll
        for (int r = 0; r < 4; ++r) {
            int qg = q0 + 16 * w + 4 * g + r;
            out[((size_t)b * LL + qg) * EE + h * DD + 16 * u + q15] = Oacc[u][r] * invl[r];
        }
    }
}

extern "C" void kernel_launch(void* const* d_in, const int* in_sizes, int n_in,
                              void* d_out, int out_size, void* d_ws, size_t ws_size,
                              hipStream_t stream) {
    const float* query = (const float*)d_in[0];
    const float* keys  = (const float*)d_in[1];
    const float* values = (const float*)d_in[2];
    const int* pad  = (const int*)d_in[3];
    const int* cau  = (const int*)d_in[4];
    const int* bern = (const int*)d_in[5];
    const float* conv_w = (const float*)d_in[6];
    const float* conv_b = (const float*)d_in[7];
    const float* Wv = (const float*)d_in[8];
    float* outp = (float*)d_out;

    const size_t per = (size_t)BB * HH * LL * DD;  // 4,194,304 elements
    __hip_bfloat16* qcb = (__hip_bfloat16*)d_ws;
    __hip_bfloat16* ksb = qcb + per;
    __hip_bfloat16* vtb = ksb + per;

    conv_kernel<<<BB * HH * (LL / 4), 256, 0, stream>>>(query, conv_w, conv_b, qcb);
    ksoftmax_kernel<<<BB * HH, 1024, 0, stream>>>(keys, bern, ksb);
    vlin_kernel<<<BB * HH * (LL / 64), 256, 0, stream>>>(values, Wv, vtb);
    attn_mfma_kernel<<<BB * HH * 16, 256, 0, stream>>>(qcb, ksb, vtb, pad, cau, outp);
}

// Round 3
// 118.460 us; speedup vs baseline: 5.6209x; 1.3962x over previous
//
#include <hip/hip_runtime.h>
#include <hip/hip_bf16.h>
#include <math.h>

#define BB 4
#define LL 1024
#define EE 1024
#define HH 16
#define DD 64
#define NCH 8
#define CHROWS 128   // LL / NCH

typedef __attribute__((ext_vector_type(8))) short short8;
typedef __attribute__((ext_vector_type(4))) float f32x4;

static __device__ __forceinline__ unsigned short bfbits(float x) {
    __hip_bfloat16 h = __float2bfloat16(x);
    return *(unsigned short*)&h;
}

// ---------------------------------------------------------------------------
// Kernel 1: grouped 3x3 conv over (l, d) per head, + bias -> bf16 qcb[bh][l][d]
// ---------------------------------------------------------------------------
__global__ __launch_bounds__(256) void conv_kernel(
    const float* __restrict__ query,
    const float* __restrict__ conv_w,
    const float* __restrict__ conv_b,
    __hip_bfloat16* __restrict__ qcb) {
    int tid = threadIdx.x;
    int d = tid & 63;
    int lr = tid >> 6;
    int tile = blockIdx.x;                 // B*H*(L/4)
    int l0 = (tile & (LL / 4 - 1)) << 2;
    int bh = tile >> 8;
    int h = bh & (HH - 1);
    int b = bh >> 4;
    int l = l0 + lr;

    const float* w = conv_w + h * 9;
    float acc = conv_b[h];
    const float* qin = query + ((size_t)b * LL) * EE + h * DD;
    #pragma unroll
    for (int i = 0; i < 3; ++i) {
        int li = l + i - 1;
        if (li < 0 || li >= LL) continue;
        #pragma unroll
        for (int j = 0; j < 3; ++j) {
            int dj = d + j - 1;
            if (dj < 0 || dj >= DD) continue;
            acc += w[i * 3 + j] * qin[(size_t)li * EE + dj];
        }
    }
    qcb[((size_t)bh * LL + l) * DD + d] = __float2bfloat16(acc);
}

// ---------------------------------------------------------------------------
// Kernel 2a: per-chunk partial (max, sumexp) for keys column-softmax.
// grid = BH * NCH blocks, 256 threads (seg = wave covers 32 rows).
// partials: pmax/psum [bh][ch][64]
// ---------------------------------------------------------------------------
__global__ __launch_bounds__(256) void ksm_partial_kernel(
    const float* __restrict__ keys,
    const int* __restrict__ bern,
    float* __restrict__ pmax,
    float* __restrict__ psum) {
    __shared__ float sm[4][64], ss[4][64];
    int tid = threadIdx.x;
    int d = tid & 63;
    int seg = tid >> 6;
    int blk = blockIdx.x;
    int ch = blk & (NCH - 1);
    int bh = blk >> 3;
    int h = bh & (HH - 1);
    int b = bh >> 4;
    int r0 = ch * CHROWS + seg * 32;

    const float* kin = keys + ((size_t)b * LL + r0) * EE + h * DD + d;
    const int* bm = bern + (size_t)bh * LL + r0;

    float v[32];
    #pragma unroll
    for (int i = 0; i < 32; ++i) v[i] = kin[(size_t)i * EE];
    float m = -INFINITY;
    #pragma unroll
    for (int i = 0; i < 32; ++i)
        if (bm[i]) m = fmaxf(m, v[i]);
    float s = 0.f;
    #pragma unroll
    for (int i = 0; i < 32; ++i)
        if (bm[i]) s += __expf(v[i] - m);

    sm[seg][d] = m;
    ss[seg][d] = s;
    __syncthreads();
    if (seg == 0) {
        float M = sm[0][d];
        #pragma unroll
        for (int t = 1; t < 4; ++t) M = fmaxf(M, sm[t][d]);
        float S = 0.f;
        if (M > -INFINITY) {
            #pragma unroll
            for (int t = 0; t < 4; ++t)
                if (sm[t][d] > -INFINITY) S += ss[t][d] * __expf(sm[t][d] - M);
        }
        pmax[(size_t)blk * 64 + d] = M;
        psum[(size_t)blk * 64 + d] = S;
    }
}

// ---------------------------------------------------------------------------
// Kernel 2b: combine chunk partials -> global (M, S) per (bh,d); normalize
// chunk and write bf16 ksb[bh][l][d] (masked rows -> 0).
// ---------------------------------------------------------------------------
__global__ __launch_bounds__(256) void ksm_final_kernel(
    const float* __restrict__ keys,
    const int* __restrict__ bern,
    const float* __restrict__ pmax,
    const float* __restrict__ psum,
    __hip_bfloat16* __restrict__ ksb) {
    int tid = threadIdx.x;
    int d = tid & 63;
    int seg = tid >> 6;
    int blk = blockIdx.x;
    int ch = blk & (NCH - 1);
    int bh = blk >> 3;
    int h = bh & (HH - 1);
    int b = bh >> 4;
    int r0 = ch * CHROWS + seg * 32;

    const float* pm = pmax + (size_t)bh * NCH * 64;
    const float* ps = psum + (size_t)bh * NCH * 64;
    float M = -INFINITY;
    #pragma unroll
    for (int c = 0; c < NCH; ++c) M = fmaxf(M, pm[c * 64 + d]);
    float S = 0.f;
    #pragma unroll
    for (int c = 0; c < NCH; ++c) {
        float mi = pm[c * 64 + d];
        if (mi > -INFINITY) S += ps[c * 64 + d] * __expf(mi - M);
    }
    float inv = 1.f / S;

    const float* kin = keys + ((size_t)b * LL + r0) * EE + h * DD + d;
    const int* bm = bern + (size_t)bh * LL + r0;
    __hip_bfloat16* kout = ksb + ((size_t)bh * LL + r0) * DD + d;
    #pragma unroll
    for (int i = 0; i < 32; ++i) {
        float val = bm[i] ? __expf(kin[(size_t)i * EE] - M) * inv : 0.f;
        kout[(size_t)i * DD] = __float2bfloat16(val);
    }
}

// ---------------------------------------------------------------------------
// Kernel 3: per-head value linear -> TRANSPOSED bf16 vt[bh][d][l]
// ---------------------------------------------------------------------------
__global__ __launch_bounds__(256) void vlin_kernel(
    const float* __restrict__ values,
    const float* __restrict__ Wv,
    __hip_bfloat16* __restrict__ vt) {
    __shared__ float WvS[64][65];
    __shared__ float vs[64][68];
    int tid = threadIdx.x;
    int tile = blockIdx.x;                 // B*H*(L/64) = 1024
    int lt = tile & 15;
    int bh = tile >> 4;
    int h = bh & (HH - 1);
    int b = bh >> 4;
    int l0 = lt * 64;

    for (int idx = tid; idx < 64 * 64; idx += 256)
        WvS[idx >> 6][idx & 63] = Wv[idx];
    const float* vin = values + ((size_t)b * LL + l0) * EE + h * DD;
    for (int idx = tid; idx < 1024; idx += 256) {
        int r = idx >> 4;
        int c4 = (idx & 15) << 2;
        *(float4*)&vs[r][c4] = *(const float4*)&vin[(size_t)r * EE + c4];
    }
    __syncthreads();

    int d = tid & 63;
    int r0 = (tid >> 6) * 16;
    float acc[16];
    #pragma unroll
    for (int r = 0; r < 16; ++r) acc[r] = 0.f;
    for (int k = 0; k < 64; ++k) {
        float wv = WvS[d][k];
        #pragma unroll
        for (int r = 0; r < 16; ++r) acc[r] += vs[r0 + r][k] * wv;
    }
    union { unsigned short us[16]; uint4 v[2]; } pk;
    #pragma unroll
    for (int r = 0; r < 16; ++r) pk.us[r] = bfbits(acc[r]);
    __hip_bfloat16* vo = vt + ((size_t)bh * DD + d) * LL + l0 + r0;
    *(uint4*)&vo[0] = pk.v[0];
    *(uint4*)&vo[8] = pk.v[1];
}

// ---------------------------------------------------------------------------
// Kernel 4: MFMA flash attention. 4 waves x 16 q-rows; kv tiles of 64.
// ---------------------------------------------------------------------------
__global__ __launch_bounds__(256) void attn_mfma_kernel(
    const __hip_bfloat16* __restrict__ qcb,
    const __hip_bfloat16* __restrict__ ksb,
    const __hip_bfloat16* __restrict__ vtb,
    const int* __restrict__ pad,
    const int* __restrict__ cau,
    float* __restrict__ out) {
    __shared__ __align__(16) short Qs[64 * 64];
    __shared__ __align__(16) short Ks[64 * 64];
    __shared__ __align__(16) short Vts[64 * 64];
    __shared__ __align__(16) short Ps[4][16 * 72];
    __shared__ int smask[64];

    int tid = threadIdx.x;
    int lane = tid & 63;
    int w = tid >> 6;
    int g = lane >> 4;
    int q15 = lane & 15;
    int qt = blockIdx.x & 15;
    int bh = blockIdx.x >> 4;
    int b = bh >> 4;
    int h = bh & 15;
    int q0 = qt * 64;

    const __hip_bfloat16* qsrc = qcb + ((size_t)bh * LL + q0) * DD;
    #pragma unroll
    for (int it = 0; it < 2; ++it) {
        int slot = it * 256 + tid;
        int row = slot >> 3, ch = slot & 7;
        const __hip_bfloat16* gp = qsrc + row * DD + ((ch ^ (row & 7)) << 3);
        __builtin_amdgcn_global_load_lds(
            (const __attribute__((address_space(1))) void*)gp,
            (__attribute__((address_space(3))) void*)(Qs + it * 2048 + w * 512),
            16, 0, 0);
    }

    f32x4 Oacc[4];
    float mrun[4], lrun[4];
    #pragma unroll
    for (int u = 0; u < 4; ++u) Oacc[u] = (f32x4){0.f, 0.f, 0.f, 0.f};
    #pragma unroll
    for (int r = 0; r < 4; ++r) { mrun[r] = -INFINITY; lrun[r] = 0.f; }
    const float inv32 = 0.03125f;

    const int* pb = pad + b * LL;
    const int* cb = cau + b * LL;
    short8 Qf0, Qf1;

    for (int kt = 0; kt < 16; ++kt) {
        int k0 = kt * 64;
        const __hip_bfloat16* ksrc = ksb + ((size_t)bh * LL + k0) * DD;
        const __hip_bfloat16* vsrc = vtb + (size_t)bh * DD * LL + k0;
        #pragma unroll
        for (int it = 0; it < 2; ++it) {
            int slot = it * 256 + tid;
            int row = slot >> 3, ch = slot & 7;
            int sw = (ch ^ (row & 7)) << 3;
            __builtin_amdgcn_global_load_lds(
                (const __attribute__((address_space(1))) void*)(ksrc + row * DD + sw),
                (__attribute__((address_space(3))) void*)(Ks + it * 2048 + w * 512),
                16, 0, 0);
            __builtin_amdgcn_global_load_lds(
                (const __attribute__((address_space(1))) void*)(vsrc + (size_t)row * LL + sw),
                (__attribute__((address_space(3))) void*)(Vts + it * 2048 + w * 512),
                16, 0, 0);
        }
        if (tid < 64)
            smask[tid] = (pb[k0 + tid] != 0) & (cb[k0 + tid] != 0);
        __syncthreads();

        if (kt == 0) {
            int qrow = 16 * w + q15;
            Qf0 = *(const short8*)&Qs[qrow * 64 + (((g + 0) ^ (q15 & 7)) << 3)];
            Qf1 = *(const short8*)&Qs[qrow * 64 + (((g + 4) ^ (q15 & 7)) << 3)];
        }

        f32x4 Sacc[4];
        #pragma unroll
        for (int t = 0; t < 4; ++t) Sacc[t] = (f32x4){0.f, 0.f, 0.f, 0.f};
        #pragma unroll
        for (int t = 0; t < 4; ++t) {
            int krow = 16 * t + q15;
            short8 Kf0 = *(const short8*)&Ks[krow * 64 + (((g + 0) ^ (q15 & 7)) << 3)];
            short8 Kf1 = *(const short8*)&Ks[krow * 64 + (((g + 4) ^ (q15 & 7)) << 3)];
            Sacc[t] = __builtin_amdgcn_mfma_f32_16x16x32_bf16(Qf0, Kf0, Sacc[t], 0, 0, 0);
            Sacc[t] = __builtin_amdgcn_mfma_f32_16x16x32_bf16(Qf1, Kf1, Sacc[t], 0, 0, 0);
        }

        #pragma unroll
        for (int t = 0; t < 4; ++t)
            if (smask[16 * t + q15]) {
                Sacc[t][0] = -1e20f; Sacc[t][1] = -1e20f;
                Sacc[t][2] = -1e20f; Sacc[t][3] = -1e20f;
            }

        #pragma unroll
        for (int r = 0; r < 4; ++r) {
            float mx = fmaxf(fmaxf(Sacc[0][r], Sacc[1][r]), fmaxf(Sacc[2][r], Sacc[3][r]));
            #pragma unroll
            for (int msk = 1; msk < 16; msk <<= 1)
                mx = fmaxf(mx, __shfl_xor(mx, msk, 64));
            float mnew = fmaxf(mrun[r], mx);
            float sc = __expf((mrun[r] - mnew) * inv32);
            float pr0 = __expf((Sacc[0][r] - mnew) * inv32);
            float pr1 = __expf((Sacc[1][r] - mnew) * inv32);
            float pr2 = __expf((Sacc[2][r] - mnew) * inv32);
            float pr3 = __expf((Sacc[3][r] - mnew) * inv32);
            float rs = pr0 + pr1 + pr2 + pr3;
            #pragma unroll
            for (int msk = 1; msk < 16; msk <<= 1)
                rs += __shfl_xor(rs, msk, 64);
            lrun[r] = lrun[r] * sc + rs;
            mrun[r] = mnew;
            #pragma unroll
            for (int u = 0; u < 4; ++u) Oacc[u][r] *= sc;
            int prow = (4 * g + r) * 72;
            Ps[w][prow + 0  + q15] = (short)bfbits(pr0);
            Ps[w][prow + 16 + q15] = (short)bfbits(pr1);
            Ps[w][prow + 32 + q15] = (short)bfbits(pr2);
            Ps[w][prow + 48 + q15] = (short)bfbits(pr3);
        }
        __syncthreads();

        short8 Pf0 = *(const short8*)&Ps[w][q15 * 72 + 8 * g];
        short8 Pf1 = *(const short8*)&Ps[w][q15 * 72 + 8 * g + 32];
        #pragma unroll
        for (int u = 0; u < 4; ++u) {
            int vrow = 16 * u + q15;
            short8 Vf0 = *(const short8*)&Vts[vrow * 64 + (((g + 0) ^ (q15 & 7)) << 3)];
            short8 Vf1 = *(const short8*)&Vts[vrow * 64 + (((g + 4) ^ (q15 & 7)) << 3)];
            Oacc[u] = __builtin_amdgcn_mfma_f32_16x16x32_bf16(Pf0, Vf0, Oacc[u], 0, 0, 0);
            Oacc[u] = __builtin_amdgcn_mfma_f32_16x16x32_bf16(Pf1, Vf1, Oacc[u], 0, 0, 0);
        }
        __syncthreads();
    }

    float invl[4];
    #pragma unroll
    for (int r = 0; r < 4; ++r) invl[r] = 1.f / lrun[r];
    #pragma unroll
    for (int u = 0; u < 4; ++u) {
        #pragma unroll
        for (int r = 0; r < 4; ++r) {
            int qg = q0 + 16 * w + 4 * g + r;
            out[((size_t)b * LL + qg) * EE + h * DD + 16 * u + q15] = Oacc[u][r] * invl[r];
        }
    }
}

extern "C" void kernel_launch(void* const* d_in, const int* in_sizes, int n_in,
                              void* d_out, int out_size, void* d_ws, size_t ws_size,
                              hipStream_t stream) {
    const float* query = (const float*)d_in[0];
    const float* keys  = (const float*)d_in[1];
    const float* values = (const float*)d_in[2];
    const int* pad  = (const int*)d_in[3];
    const int* cau  = (const int*)d_in[4];
    const int* bern = (const int*)d_in[5];
    const float* conv_w = (const float*)d_in[6];
    const float* conv_b = (const float*)d_in[7];
    const float* Wv = (const float*)d_in[8];
    float* outp = (float*)d_out;

    const size_t per = (size_t)BB * HH * LL * DD;  // 4,194,304 elements
    __hip_bfloat16* qcb = (__hip_bfloat16*)d_ws;
    __hip_bfloat16* ksb = qcb + per;
    __hip_bfloat16* vtb = ksb + per;
    float* pmax = (float*)(vtb + per);             // [BH][NCH][64]
    float* psum = pmax + (size_t)BB * HH * NCH * 64;

    conv_kernel<<<BB * HH * (LL / 4), 256, 0, stream>>>(query, conv_w, conv_b, qcb);
    ksm_partial_kernel<<<BB * HH * NCH, 256, 0, stream>>>(keys, bern, pmax, psum);
    ksm_final_kernel<<<BB * HH * NCH, 256, 0, stream>>>(keys, bern, pmax, psum, ksb);
    vlin_kernel<<<BB * HH * (LL / 64), 256, 0, stream>>>(values, Wv, vtb);
    attn_mfma_kernel<<<BB * HH * 16, 256, 0, stream>>>(qcb, ksb, vtb, pad, cau, outp);
}

// Round 4
// 107.909 us; speedup vs baseline: 6.1705x; 1.0978x over previous
//
#include <hip/hip_runtime.h>
#include <hip/hip_bf16.h>
#include <math.h>

#define BB 4
#define LL 1024
#define EE 1024
#define HH 16
#define DD 64
#define NCH 8
#define CHROWS 128   // LL / NCH
#define K2C 0.04508422002777998f   // log2(e)/32

typedef __attribute__((ext_vector_type(8))) short short8;
typedef __attribute__((ext_vector_type(4))) float f32x4;
typedef __attribute__((ext_vector_type(16))) float f32x16;
typedef __attribute__((ext_vector_type(4))) int int4v;

static __device__ __forceinline__ unsigned short bfbits(float x) {
    __hip_bfloat16 h = __float2bfloat16(x);
    return *(unsigned short*)&h;
}

#define CVTPK(dst, lo_, hi_) \
    asm("v_cvt_pk_bf16_f32 %0, %1, %2" : "=v"(dst) : "v"(lo_), "v"(hi_))
#define PLSWAP(x_, y_) \
    asm("v_permlane32_swap_b32 %0, %1" : "+v"(x_), "+v"(y_))

// ---------------------------------------------------------------------------
// Kernel 1: grouped 3x3 conv over (l, d) per head, + bias -> bf16 qcb[bh][l][d]
// ---------------------------------------------------------------------------
__global__ __launch_bounds__(256) void conv_kernel(
    const float* __restrict__ query,
    const float* __restrict__ conv_w,
    const float* __restrict__ conv_b,
    __hip_bfloat16* __restrict__ qcb) {
    int tid = threadIdx.x;
    int d = tid & 63;
    int lr = tid >> 6;
    int tile = blockIdx.x;                 // B*H*(L/4)
    int l0 = (tile & (LL / 4 - 1)) << 2;
    int bh = tile >> 8;
    int h = bh & (HH - 1);
    int b = bh >> 4;
    int l = l0 + lr;

    const float* w = conv_w + h * 9;
    float acc = conv_b[h];
    const float* qin = query + ((size_t)b * LL) * EE + h * DD;
    #pragma unroll
    for (int i = 0; i < 3; ++i) {
        int li = l + i - 1;
        if (li < 0 || li >= LL) continue;
        #pragma unroll
        for (int j = 0; j < 3; ++j) {
            int dj = d + j - 1;
            if (dj < 0 || dj >= DD) continue;
            acc += w[i * 3 + j] * qin[(size_t)li * EE + dj];
        }
    }
    qcb[((size_t)bh * LL + l) * DD + d] = __float2bfloat16(acc);
}

// ---------------------------------------------------------------------------
// Kernel 2a: per-chunk partial (max, sumexp) for keys column-softmax.
// ---------------------------------------------------------------------------
__global__ __launch_bounds__(256) void ksm_partial_kernel(
    const float* __restrict__ keys,
    const int* __restrict__ bern,
    float* __restrict__ pmax,
    float* __restrict__ psum) {
    __shared__ float sm[4][64], ss[4][64];
    int tid = threadIdx.x;
    int d = tid & 63;
    int seg = tid >> 6;
    int blk = blockIdx.x;
    int ch = blk & (NCH - 1);
    int bh = blk >> 3;
    int h = bh & (HH - 1);
    int b = bh >> 4;
    int r0 = ch * CHROWS + seg * 32;

    const float* kin = keys + ((size_t)b * LL + r0) * EE + h * DD + d;
    const int* bm = bern + (size_t)bh * LL + r0;

    float v[32];
    #pragma unroll
    for (int i = 0; i < 32; ++i) v[i] = kin[(size_t)i * EE];
    float m = -INFINITY;
    #pragma unroll
    for (int i = 0; i < 32; ++i)
        if (bm[i]) m = fmaxf(m, v[i]);
    float s = 0.f;
    #pragma unroll
    for (int i = 0; i < 32; ++i)
        if (bm[i]) s += __expf(v[i] - m);

    sm[seg][d] = m;
    ss[seg][d] = s;
    __syncthreads();
    if (seg == 0) {
        float M = sm[0][d];
        #pragma unroll
        for (int t = 1; t < 4; ++t) M = fmaxf(M, sm[t][d]);
        float S = 0.f;
        if (M > -INFINITY) {
            #pragma unroll
            for (int t = 0; t < 4; ++t)
                if (sm[t][d] > -INFINITY) S += ss[t][d] * __expf(sm[t][d] - M);
        }
        pmax[(size_t)blk * 64 + d] = M;
        psum[(size_t)blk * 64 + d] = S;
    }
}

// ---------------------------------------------------------------------------
// Kernel 2b: combine chunk partials; normalize chunk; write bf16 ksb.
// ---------------------------------------------------------------------------
__global__ __launch_bounds__(256) void ksm_final_kernel(
    const float* __restrict__ keys,
    const int* __restrict__ bern,
    const float* __restrict__ pmax,
    const float* __restrict__ psum,
    __hip_bfloat16* __restrict__ ksb) {
    int tid = threadIdx.x;
    int d = tid & 63;
    int seg = tid >> 6;
    int blk = blockIdx.x;
    int ch = blk & (NCH - 1);
    int bh = blk >> 3;
    int h = bh & (HH - 1);
    int b = bh >> 4;
    int r0 = ch * CHROWS + seg * 32;

    const float* pm = pmax + (size_t)bh * NCH * 64;
    const float* ps = psum + (size_t)bh * NCH * 64;
    float M = -INFINITY;
    #pragma unroll
    for (int c = 0; c < NCH; ++c) M = fmaxf(M, pm[c * 64 + d]);
    float S = 0.f;
    #pragma unroll
    for (int c = 0; c < NCH; ++c) {
        float mi = pm[c * 64 + d];
        if (mi > -INFINITY) S += ps[c * 64 + d] * __expf(mi - M);
    }
    float inv = 1.f / S;

    const float* kin = keys + ((size_t)b * LL + r0) * EE + h * DD + d;
    const int* bm = bern + (size_t)bh * LL + r0;
    __hip_bfloat16* kout = ksb + ((size_t)bh * LL + r0) * DD + d;
    #pragma unroll
    for (int i = 0; i < 32; ++i) {
        float val = bm[i] ? __expf(kin[(size_t)i * EE] - M) * inv : 0.f;
        kout[(size_t)i * DD] = __float2bfloat16(val);
    }
}

// ---------------------------------------------------------------------------
// Kernel 3: per-head value linear -> TRANSPOSED bf16 vt[bh][d][l]
// ---------------------------------------------------------------------------
__global__ __launch_bounds__(256) void vlin_kernel(
    const float* __restrict__ values,
    const float* __restrict__ Wv,
    __hip_bfloat16* __restrict__ vt) {
    __shared__ float WvS[64][65];
    __shared__ float vs[64][68];
    int tid = threadIdx.x;
    int tile = blockIdx.x;                 // B*H*(L/64) = 1024
    int lt = tile & 15;
    int bh = tile >> 4;
    int h = bh & (HH - 1);
    int b = bh >> 4;
    int l0 = lt * 64;

    for (int idx = tid; idx < 64 * 64; idx += 256)
        WvS[idx >> 6][idx & 63] = Wv[idx];
    const float* vin = values + ((size_t)b * LL + l0) * EE + h * DD;
    for (int idx = tid; idx < 1024; idx += 256) {
        int r = idx >> 4;
        int c4 = (idx & 15) << 2;
        *(float4*)&vs[r][c4] = *(const float4*)&vin[(size_t)r * EE + c4];
    }
    __syncthreads();

    int d = tid & 63;
    int r0 = (tid >> 6) * 16;
    float acc[16];
    #pragma unroll
    for (int r = 0; r < 16; ++r) acc[r] = 0.f;
    for (int k = 0; k < 64; ++k) {
        float wv = WvS[d][k];
        #pragma unroll
        for (int r = 0; r < 16; ++r) acc[r] += vs[r0 + r][k] * wv;
    }
    union { unsigned short us[16]; uint4 v[2]; } pk;
    #pragma unroll
    for (int r = 0; r < 16; ++r) pk.us[r] = bfbits(acc[r]);
    __hip_bfloat16* vo = vt + ((size_t)bh * DD + d) * LL + l0 + r0;
    *(uint4*)&vo[0] = pk.v[0];
    *(uint4*)&vo[8] = pk.v[1];
}

// ---------------------------------------------------------------------------
// Kernel 4: swapped-QK^T MFMA flash attention (32x32x16, in-register softmax).
// 8 waves x 32 q-rows = 256 q/block; KVBLK=64 double-buffered.
// ---------------------------------------------------------------------------
__global__ __launch_bounds__(512) void attn_mfma_kernel(
    const __hip_bfloat16* __restrict__ qcb,
    const __hip_bfloat16* __restrict__ ksb,
    const __hip_bfloat16* __restrict__ vtb,
    const int* __restrict__ pad,
    const int* __restrict__ cau,
    float* __restrict__ out) {
    __shared__ __align__(16) short KsS[2][4096];
    __shared__ __align__(16) short VtS[2][4096];
    __shared__ __align__(16) float OutS[8][32 * 36];
    __shared__ int smaskS[2][64];

    int tid = threadIdx.x;
    int lane = tid & 63;
    int w = tid >> 6;
    int q5 = lane & 31;
    int hi = lane >> 5;

    int bid = blockIdx.x;
    int swz = (bid & 7) * 32 + (bid >> 3);   // 8 XCDs x 32: each XCD owns 8 bh
    int bh = swz >> 2;
    int qb = swz & 3;
    int b = bh >> 4;
    int h = bh & 15;
    int q0w = qb * 256 + w * 32;

    const int* pb = pad + b * LL;
    const int* cb = cau + b * LL;

    int srow = tid >> 3;
    int sch = tid & 7;
    int ssw = (sch ^ (srow & 7)) << 3;
    const __hip_bfloat16* kg = ksb + (size_t)bh * LL * DD + (size_t)srow * DD + ssw;
    const __hip_bfloat16* vg = vtb + (size_t)bh * DD * LL + (size_t)srow * LL + ssw;

    short8 Qf[4];
    {
        const __hip_bfloat16* qrow = qcb + ((size_t)bh * LL + q0w + q5) * DD + 8 * hi;
        #pragma unroll
        for (int i = 0; i < 4; ++i)
            Qf[i] = *(const short8*)(qrow + 16 * i);
    }

    __builtin_amdgcn_global_load_lds(
        (const __attribute__((address_space(1))) void*)kg,
        (__attribute__((address_space(3))) void*)&KsS[0][w * 512], 16, 0, 0);
    __builtin_amdgcn_global_load_lds(
        (const __attribute__((address_space(1))) void*)vg,
        (__attribute__((address_space(3))) void*)&VtS[0][w * 512], 16, 0, 0);
    if (tid < 64) smaskS[0][tid] = (pb[tid] != 0) & (cb[tid] != 0);
    __syncthreads();

    f32x16 O0, O1;
    #pragma unroll
    for (int e = 0; e < 16; ++e) { O0[e] = 0.f; O1[e] = 0.f; }
    float mrun = -INFINITY, lrun = 0.f;

    for (int kt = 0; kt < 16; ++kt) {
        int buf = kt & 1;
        if (kt < 15) {
            int k0n = (kt + 1) * 64;
            __builtin_amdgcn_global_load_lds(
                (const __attribute__((address_space(1))) void*)(kg + (size_t)k0n * DD),
                (__attribute__((address_space(3))) void*)&KsS[buf ^ 1][w * 512], 16, 0, 0);
            __builtin_amdgcn_global_load_lds(
                (const __attribute__((address_space(1))) void*)(vg + k0n),
                (__attribute__((address_space(3))) void*)&VtS[buf ^ 1][w * 512], 16, 0, 0);
            if (tid < 64)
                smaskS[buf ^ 1][tid] = (pb[k0n + tid] != 0) & (cb[k0n + tid] != 0);
        }

        const short* Kb = KsS[buf];
        const short* Vb = VtS[buf];
        int rsw = q5 & 7;

        f32x16 S0, S1;
        #pragma unroll
        for (int e = 0; e < 16; ++e) { S0[e] = 0.f; S1[e] = 0.f; }
        #pragma unroll
        for (int i = 0; i < 4; ++i) {
            int c = 2 * i + hi;
            int off = (c ^ rsw) << 3;
            short8 Ka0 = *(const short8*)&Kb[q5 * 64 + off];
            short8 Ka1 = *(const short8*)&Kb[(32 + q5) * 64 + off];
            S0 = __builtin_amdgcn_mfma_f32_32x32x16_bf16(Ka0, Qf[i], S0, 0, 0, 0);
            S1 = __builtin_amdgcn_mfma_f32_32x32x16_bf16(Ka1, Qf[i], S1, 0, 0, 0);
        }

        float s[32];
        const int* mk0 = smaskS[buf];
        #pragma unroll
        for (int r = 0; r < 16; ++r) {
            int kl = (r & 3) + 8 * (r >> 2) + 4 * hi;
            s[r]      = mk0[kl]      ? -1e20f : S0[r];
            s[16 + r] = mk0[32 + kl] ? -1e20f : S1[r];
        }

        float m16[16];
        #pragma unroll
        for (int r = 0; r < 16; ++r) m16[r] = fmaxf(s[r], s[16 + r]);
        float m8[8];
        #pragma unroll
        for (int r = 0; r < 8; ++r) m8[r] = fmaxf(m16[r], m16[r + 8]);
        float m4[4];
        #pragma unroll
        for (int r = 0; r < 4; ++r) m4[r] = fmaxf(m8[r], m8[r + 4]);
        float mx = fmaxf(fmaxf(m4[0], m4[1]), fmaxf(m4[2], m4[3]));
        mx = fmaxf(mx, __shfl_xor(mx, 32, 64));

        float mnew = fmaxf(mrun, mx);
        float mkc = mnew * K2C;
        float sc = exp2f(mrun * K2C - mkc);

        float pv[32];
        #pragma unroll
        for (int r = 0; r < 32; ++r) pv[r] = exp2f(s[r] * K2C - mkc);

        float t16[16];
        #pragma unroll
        for (int r = 0; r < 16; ++r) t16[r] = pv[r] + pv[r + 16];
        float t8[8];
        #pragma unroll
        for (int r = 0; r < 8; ++r) t8[r] = t16[r] + t16[r + 8];
        float t4[4];
        #pragma unroll
        for (int r = 0; r < 4; ++r) t4[r] = t8[r] + t8[r + 4];
        float rs = (t4[0] + t4[1]) + (t4[2] + t4[3]);
        rs += __shfl_xor(rs, 32, 64);

        lrun = lrun * sc + rs;
        mrun = mnew;
        #pragma unroll
        for (int e = 0; e < 16; ++e) { O0[e] *= sc; O1[e] *= sc; }

        union PW { int4v i4; short8 s8; } pa[4];
        #pragma unroll
        for (int st = 0; st < 2; ++st) {
            int a0, b0, a1, b1, a2, b2, a3, b3;
            CVTPK(a0, pv[16 * st + 0], pv[16 * st + 1]);
            CVTPK(b0, pv[16 * st + 4], pv[16 * st + 5]);
            PLSWAP(a0, b0);
            CVTPK(a1, pv[16 * st + 2], pv[16 * st + 3]);
            CVTPK(b1, pv[16 * st + 6], pv[16 * st + 7]);
            PLSWAP(a1, b1);
            pa[2 * st].i4 = (int4v){a0, a1, b0, b1};
            CVTPK(a2, pv[16 * st + 8], pv[16 * st + 9]);
            CVTPK(b2, pv[16 * st + 12], pv[16 * st + 13]);
            PLSWAP(a2, b2);
            CVTPK(a3, pv[16 * st + 10], pv[16 * st + 11]);
            CVTPK(b3, pv[16 * st + 14], pv[16 * st + 15]);
            PLSWAP(a3, b3);
            pa[2 * st + 1].i4 = (int4v){a2, a3, b2, b3};
        }

        #pragma unroll
        for (int ks = 0; ks < 4; ++ks) {
            int c = 2 * ks + hi;
            int off = (c ^ rsw) << 3;
            short8 Va0 = *(const short8*)&Vb[q5 * 64 + off];
            short8 Va1 = *(const short8*)&Vb[(32 + q5) * 64 + off];
            O0 = __builtin_amdgcn_mfma_f32_32x32x16_bf16(Va0, pa[ks].s8, O0, 0, 0, 0);
            O1 = __builtin_amdgcn_mfma_f32_32x32x16_bf16(Va1, pa[ks].s8, O1, 0, 0, 0);
        }

        if (kt < 15) __syncthreads();
    }

    float invl = 1.f / lrun;
    float* oreg = OutS[w];
    int orow = lane >> 1;
    int ocol = (lane & 1) * 16;

    #pragma unroll
    for (int r = 0; r < 16; ++r) {
        int dl = (r & 3) + 8 * (r >> 2) + 4 * hi;
        oreg[q5 * 36 + dl] = O0[r];
    }
    if (hi == 0) oreg[q5 * 36 + 32] = invl;
    asm volatile("" ::: "memory");
    {
        float iv = oreg[orow * 36 + 32];
        float* gout = out + ((size_t)b * LL + q0w + orow) * EE + h * DD + ocol;
        #pragma unroll
        for (int c = 0; c < 4; ++c) {
            float4 vv = *(float4*)&oreg[orow * 36 + ocol + 4 * c];
            vv.x *= iv; vv.y *= iv; vv.z *= iv; vv.w *= iv;
            *(float4*)&gout[4 * c] = vv;
        }
    }
    asm volatile("" ::: "memory");
    #pragma unroll
    for (int r = 0; r < 16; ++r) {
        int dl = (r & 3) + 8 * (r >> 2) + 4 * hi;
        oreg[q5 * 36 + dl] = O1[r];
    }
    asm volatile("" ::: "memory");
    {
        float iv = oreg[orow * 36 + 32];
        float* gout = out + ((size_t)b * LL + q0w + orow) * EE + h * DD + 32 + ocol;
        #pragma unroll
        for (int c = 0; c < 4; ++c) {
            float4 vv = *(float4*)&oreg[orow * 36 + ocol + 4 * c];
            vv.x *= iv; vv.y *= iv; vv.z *= iv; vv.w *= iv;
            *(float4*)&gout[4 * c] = vv;
        }
    }
}

extern "C" void kernel_launch(void* const* d_in, const int* in_sizes, int n_in,
                              void* d_out, int out_size, void* d_ws, size_t ws_size,
                              hipStream_t stream) {
    const float* query = (const float*)d_in[0];
    const float* keys  = (const float*)d_in[1];
    const float* values = (const float*)d_in[2];
    const int* pad  = (const int*)d_in[3];
    const int* cau  = (const int*)d_in[4];
    const int* bern = (const int*)d_in[5];
    const float* conv_w = (const float*)d_in[6];
    const float* conv_b = (const float*)d_in[7];
    const float* Wv = (const float*)d_in[8];
    float* outp = (float*)d_out;

    const size_t per = (size_t)BB * HH * LL * DD;
    __hip_bfloat16* qcb = (__hip_bfloat16*)d_ws;
    __hip_bfloat16* ksb = qcb + per;
    __hip_bfloat16* vtb = ksb + per;
    float* pmax = (float*)(vtb + per);
    float* psum = pmax + (size_t)BB * HH * NCH * 64;

    conv_kernel<<<BB * HH * (LL / 4), 256, 0, stream>>>(query, conv_w, conv_b, qcb);
    ksm_partial_kernel<<<BB * HH * NCH, 256, 0, stream>>>(keys, bern, pmax, psum);
    ksm_final_kernel<<<BB * HH * NCH, 256, 0, stream>>>(keys, bern, pmax, psum, ksb);
    vlin_kernel<<<BB * HH * (LL / 64), 256, 0, stream>>>(values, Wv, vtb);
    attn_mfma_kernel<<<BB * HH * 4, 512, 0, stream>>>(qcb, ksb, vtb, pad, cau, outp);
}